// Round 21
// baseline (139.755 us; speedup 1.0000x reference)
//
#include <hip/hip_runtime.h>
#include <math.h>

#define Bv  4
#define Cv  64
#define DCv 32
#define Fv  128
#define Tv  512
#define FT  (Fv * 512)

// ---------------------------------------------------------------------------
// KC1: conv1, 8-row x 4-t register tile (~27 us). [BYTE-IDENTICAL to r20]
// ---------------------------------------------------------------------------
__global__ __launch_bounds__(256, 4)
void kc1_conv(const float* __restrict__ inp,
              const float* __restrict__ w1, const float* __restrict__ b1,
              const float* __restrict__ g1, const float* __restrict__ be1,
              const float* __restrict__ m1, const float* __restrict__ v1,
              const float* __restrict__ a1,
              float* __restrict__ Qws)
{
    __shared__ __align__(16) float sW[Cv * DCv];   // 8 KB [k][c]
    __shared__ float sB[DCv];

    const int tid = threadIdx.x;
    const int bid = blockIdx.x;
    const int h   = bid & 1;
    const int bf  = bid >> 1;
    const int b   = bf >> 7;
    const int f   = bf & 127;

    #pragma unroll
    for (int i = 0; i < 8; ++i) {
        const int e = tid * 8 + i;
        const int c = e & 31, k = e >> 5;
        sW[e] = w1[c * Cv + k] * (g1[c] * rsqrtf(v1[c] + 1e-5f));
    }
    if (tid < DCv) {
        const float s = g1[tid] * rsqrtf(v1[tid] + 1e-5f);
        sB[tid] = (b1[tid] - m1[tid]) * s + be1[tid];
    }
    const float alpha1 = a1[0];
    __syncthreads();

    const int w  = tid >> 6, l = tid & 63;
    const int tl = l & 15, cl = l >> 4;
    const int r0 = cl * 8;
    const int t0 = h * 256 + w * 64 + tl * 4;

    const float* px = inp + (size_t)(b * Cv) * FT + f * 512 + t0;

    float acc[32];
    #pragma unroll
    for (int i = 0; i < 32; ++i) acc[i] = 0.f;

    #pragma unroll 8
    for (int k = 0; k < Cv; ++k) {
        const float4 x   = *(const float4*)&px[(size_t)k * FT];
        const float4 a0  = *(const float4*)&sW[k * DCv + r0];
        const float4 a1v = *(const float4*)&sW[k * DCv + r0 + 4];
        acc[0*4+0] = fmaf(a0.x, x.x, acc[0*4+0]); acc[0*4+1] = fmaf(a0.x, x.y, acc[0*4+1]);
        acc[0*4+2] = fmaf(a0.x, x.z, acc[0*4+2]); acc[0*4+3] = fmaf(a0.x, x.w, acc[0*4+3]);
        acc[1*4+0] = fmaf(a0.y, x.x, acc[1*4+0]); acc[1*4+1] = fmaf(a0.y, x.y, acc[1*4+1]);
        acc[1*4+2] = fmaf(a0.y, x.z, acc[1*4+2]); acc[1*4+3] = fmaf(a0.y, x.w, acc[1*4+3]);
        acc[2*4+0] = fmaf(a0.z, x.x, acc[2*4+0]); acc[2*4+1] = fmaf(a0.z, x.y, acc[2*4+1]);
        acc[2*4+2] = fmaf(a0.z, x.z, acc[2*4+2]); acc[2*4+3] = fmaf(a0.z, x.w, acc[2*4+3]);
        acc[3*4+0] = fmaf(a0.w, x.x, acc[3*4+0]); acc[3*4+1] = fmaf(a0.w, x.y, acc[3*4+1]);
        acc[3*4+2] = fmaf(a0.w, x.z, acc[3*4+2]); acc[3*4+3] = fmaf(a0.w, x.w, acc[3*4+3]);
        acc[4*4+0] = fmaf(a1v.x, x.x, acc[4*4+0]); acc[4*4+1] = fmaf(a1v.x, x.y, acc[4*4+1]);
        acc[4*4+2] = fmaf(a1v.x, x.z, acc[4*4+2]); acc[4*4+3] = fmaf(a1v.x, x.w, acc[4*4+3]);
        acc[5*4+0] = fmaf(a1v.y, x.x, acc[5*4+0]); acc[5*4+1] = fmaf(a1v.y, x.y, acc[5*4+1]);
        acc[5*4+2] = fmaf(a1v.y, x.z, acc[5*4+2]); acc[5*4+3] = fmaf(a1v.y, x.w, acc[5*4+3]);
        acc[6*4+0] = fmaf(a1v.z, x.x, acc[6*4+0]); acc[6*4+1] = fmaf(a1v.z, x.y, acc[6*4+1]);
        acc[6*4+2] = fmaf(a1v.z, x.z, acc[6*4+2]); acc[6*4+3] = fmaf(a1v.z, x.w, acc[6*4+3]);
        acc[7*4+0] = fmaf(a1v.w, x.x, acc[7*4+0]); acc[7*4+1] = fmaf(a1v.w, x.y, acc[7*4+1]);
        acc[7*4+2] = fmaf(a1v.w, x.z, acc[7*4+2]); acc[7*4+3] = fmaf(a1v.w, x.w, acc[7*4+3]);
    }

    const float b0 = sB[r0+0], b1_ = sB[r0+1], b2 = sB[r0+2], b3 = sB[r0+3];
    const float b4 = sB[r0+4], b5  = sB[r0+5], b6 = sB[r0+6], b7 = sB[r0+7];
    #pragma unroll
    for (int j = 0; j < 4; ++j) {
        float z0 = acc[0*4+j] + b0, z1 = acc[1*4+j] + b1_;
        float z2 = acc[2*4+j] + b2, z3 = acc[3*4+j] + b3;
        float z4 = acc[4*4+j] + b4, z5 = acc[5*4+j] + b5;
        float z6 = acc[6*4+j] + b6, z7 = acc[7*4+j] + b7;
        z0 = z0 >= 0.f ? z0 : alpha1 * z0;  z1 = z1 >= 0.f ? z1 : alpha1 * z1;
        z2 = z2 >= 0.f ? z2 : alpha1 * z2;  z3 = z3 >= 0.f ? z3 : alpha1 * z3;
        z4 = z4 >= 0.f ? z4 : alpha1 * z4;  z5 = z5 >= 0.f ? z5 : alpha1 * z5;
        z6 = z6 >= 0.f ? z6 : alpha1 * z6;  z7 = z7 >= 0.f ? z7 : alpha1 * z7;
        float4 v0; v0.x = z0; v0.y = z1; v0.z = z2; v0.w = z3;
        float4 v1; v1.x = z4; v1.y = z5; v1.z = z6; v1.w = z7;
        float* qg = Qws + ((size_t)bf * Tv + t0 + j) * DCv + r0;
        *(float4*)&qg[0] = v0;
        *(float4*)&qg[4] = v1;
    }
}

// ---------------------------------------------------------------------------
// KM: M = Q Q^T / sqrt(32). One block per bf (~9 us). [BYTE-IDENTICAL]
// ---------------------------------------------------------------------------
__global__ __launch_bounds__(256)
void km_build(const float* __restrict__ Qws, float* __restrict__ Mfull)
{
    __shared__ __align__(16) float sP[4][1024];  // 16 KB

    const int tid   = threadIdx.x;
    const int bf    = blockIdx.x;
    const int slice = tid >> 6;
    const int l     = tid & 63;
    const int c1b   = l >> 3;
    const int c2b   = l & 7;

    const float* qp = Qws + ((size_t)bf * Tv + slice * 128) * DCv;
    float4 r0 = {0,0,0,0}, r1 = {0,0,0,0}, r2 = {0,0,0,0}, r3 = {0,0,0,0};
    #pragma unroll 4
    for (int i = 0; i < 128; ++i) {
        const float4 qa = *(const float4*)&qp[i * 32 + c1b * 4];
        const float4 qb = *(const float4*)&qp[i * 32 + c2b * 4];
        r0.x = fmaf(qa.x, qb.x, r0.x); r0.y = fmaf(qa.x, qb.y, r0.y);
        r0.z = fmaf(qa.x, qb.z, r0.z); r0.w = fmaf(qa.x, qb.w, r0.w);
        r1.x = fmaf(qa.y, qb.x, r1.x); r1.y = fmaf(qa.y, qb.y, r1.y);
        r1.z = fmaf(qa.y, qb.z, r1.z); r1.w = fmaf(qa.y, qb.w, r1.w);
        r2.x = fmaf(qa.z, qb.x, r2.x); r2.y = fmaf(qa.z, qb.y, r2.y);
        r2.z = fmaf(qa.z, qb.z, r2.z); r2.w = fmaf(qa.z, qb.w, r2.w);
        r3.x = fmaf(qa.w, qb.x, r3.x); r3.y = fmaf(qa.w, qb.y, r3.y);
        r3.z = fmaf(qa.w, qb.z, r3.z); r3.w = fmaf(qa.w, qb.w, r3.w);
    }
    *(float4*)&sP[slice][(c1b * 4 + 0) * DCv + c2b * 4] = r0;
    *(float4*)&sP[slice][(c1b * 4 + 1) * DCv + c2b * 4] = r1;
    *(float4*)&sP[slice][(c1b * 4 + 2) * DCv + c2b * 4] = r2;
    *(float4*)&sP[slice][(c1b * 4 + 3) * DCv + c2b * 4] = r3;
    __syncthreads();

    const float INV = 0.17677669529663687f;  // 1/sqrt(32)
    float4 v0 = *(const float4*)&sP[0][tid * 4];
    float4 v1 = *(const float4*)&sP[1][tid * 4];
    float4 v2 = *(const float4*)&sP[2][tid * 4];
    float4 v3 = *(const float4*)&sP[3][tid * 4];
    float4 o;
    o.x = ((v0.x + v1.x) + (v2.x + v3.x)) * INV;
    o.y = ((v0.y + v1.y) + (v2.y + v3.y)) * INV;
    o.z = ((v0.z + v1.z) + (v2.z + v3.z)) * INV;
    o.w = ((v0.w + v1.w) + (v2.w + v3.w)) * INV;
    *(float4*)&Mfull[(size_t)bf * 1024 + tid * 4] = o;
}

// ---------------------------------------------------------------------------
// KF v4: A-operands (M, raw W2) via VECTOR GLOBAL loads (vmcnt pipe; M 4KB
// and wp 8KB are L1/L2-resident) -- LDS reads drop 288 -> 96 per thread,
// unclogging the per-CU LDS pipe (r20 arithmetic: ~23 us of ds_read issue).
// BN2 scale applied AFTER accumulation (z = acc*s2 + bias2; algebra identical)
// so no weight prep needed. Online softmax kept. x-operands stay in LDS sX.
// ---------------------------------------------------------------------------
#define GEMM_CC(ACC, cc, a)                                       \
    ACC[(cc)*4+0] = fmaf(a.x, x0.x, ACC[(cc)*4+0]);               \
    ACC[(cc)*4+0] = fmaf(a.y, x1.x, ACC[(cc)*4+0]);               \
    ACC[(cc)*4+0] = fmaf(a.z, x2.x, ACC[(cc)*4+0]);               \
    ACC[(cc)*4+0] = fmaf(a.w, x3.x, ACC[(cc)*4+0]);               \
    ACC[(cc)*4+1] = fmaf(a.x, x0.y, ACC[(cc)*4+1]);               \
    ACC[(cc)*4+1] = fmaf(a.y, x1.y, ACC[(cc)*4+1]);               \
    ACC[(cc)*4+1] = fmaf(a.z, x2.y, ACC[(cc)*4+1]);               \
    ACC[(cc)*4+1] = fmaf(a.w, x3.y, ACC[(cc)*4+1]);               \
    ACC[(cc)*4+2] = fmaf(a.x, x0.z, ACC[(cc)*4+2]);               \
    ACC[(cc)*4+2] = fmaf(a.y, x1.z, ACC[(cc)*4+2]);               \
    ACC[(cc)*4+2] = fmaf(a.z, x2.z, ACC[(cc)*4+2]);               \
    ACC[(cc)*4+2] = fmaf(a.w, x3.z, ACC[(cc)*4+2]);               \
    ACC[(cc)*4+3] = fmaf(a.x, x0.w, ACC[(cc)*4+3]);               \
    ACC[(cc)*4+3] = fmaf(a.y, x1.w, ACC[(cc)*4+3]);               \
    ACC[(cc)*4+3] = fmaf(a.z, x2.w, ACC[(cc)*4+3]);               \
    ACC[(cc)*4+3] = fmaf(a.w, x3.w, ACC[(cc)*4+3]);

__global__ __launch_bounds__(512, 2)
void kf_fused(const float* __restrict__ inp,
              const float* __restrict__ Qws, const float* __restrict__ Mfull,
              const float* __restrict__ wp, const float* __restrict__ bp,
              const float* __restrict__ g2, const float* __restrict__ be2,
              const float* __restrict__ m2, const float* __restrict__ v2,
              const float* __restrict__ a2,
              float* __restrict__ out)
{
    __shared__ __align__(16) float sX[DCv * Tv];   // 64 KB [k][t]: Q, then P
    __shared__ float sPartM[8][DCv], sPartS[8][DCv];
    __shared__ float sMx[DCv], sRZ[DCv];
    __shared__ float sS2[Cv], sB2[Cv];

    const int tid = threadIdx.x;
    const int bf  = blockIdx.x;
    const int b   = bf >> 7;
    const int f   = bf & 127;
    const int w   = tid >> 6;
    const int l   = tid & 63;
    const int tl  = l & 15;
    const int cl  = l >> 4;
    const int t0  = w * 64 + tl * 4;          // this lane's 4 t-columns
    const int limit = f + (Tv - Fv + 1);      // valid iff t < limit (385..512)
    const float alpha2 = a2[0];

    // ---- stage: q column -> sX; BN2 scale/bias (tiny LDS) ----
    const float* qg = Qws + ((size_t)bf * Tv + tid) * DCv;
    float4 q0 = *(const float4*)&qg[0],  q1 = *(const float4*)&qg[4];
    float4 q2 = *(const float4*)&qg[8],  q3 = *(const float4*)&qg[12];
    float4 q4 = *(const float4*)&qg[16], q5 = *(const float4*)&qg[20];
    float4 q6 = *(const float4*)&qg[24], q7 = *(const float4*)&qg[28];

    if (tid < Cv) {
        const float s = g2[tid] * rsqrtf(v2[tid] + 1e-5f);
        sS2[tid] = s;
        sB2[tid] = (bp[tid] - m2[tid]) * s + be2[tid];
    }

    {
        const int t = tid;
        sX[ 0*Tv+t]=q0.x; sX[ 1*Tv+t]=q0.y; sX[ 2*Tv+t]=q0.z; sX[ 3*Tv+t]=q0.w;
        sX[ 4*Tv+t]=q1.x; sX[ 5*Tv+t]=q1.y; sX[ 6*Tv+t]=q1.z; sX[ 7*Tv+t]=q1.w;
        sX[ 8*Tv+t]=q2.x; sX[ 9*Tv+t]=q2.y; sX[10*Tv+t]=q2.z; sX[11*Tv+t]=q2.w;
        sX[12*Tv+t]=q3.x; sX[13*Tv+t]=q3.y; sX[14*Tv+t]=q3.z; sX[15*Tv+t]=q3.w;
        sX[16*Tv+t]=q4.x; sX[17*Tv+t]=q4.y; sX[18*Tv+t]=q4.z; sX[19*Tv+t]=q4.w;
        sX[20*Tv+t]=q5.x; sX[21*Tv+t]=q5.y; sX[22*Tv+t]=q5.z; sX[23*Tv+t]=q5.w;
        sX[24*Tv+t]=q6.x; sX[25*Tv+t]=q6.y; sX[26*Tv+t]=q6.z; sX[27*Tv+t]=q6.w;
        sX[28*Tv+t]=q7.x; sX[29*Tv+t]=q7.y; sX[30*Tv+t]=q7.z; sX[31*Tv+t]=q7.w;
    }
    __syncthreads();

    // ---- GEMM1: O[32c][t]; A from GLOBAL Mfull (L1-hot, vmcnt pipe) ----
    const float* Mg = Mfull + (size_t)bf * 1024;
    float oA[16], oB[16];
    #pragma unroll
    for (int i = 0; i < 16; ++i) { oA[i] = 0.f; oB[i] = 0.f; }
    const int cA = cl * 4;
    const int cB = 16 + cl * 4;
    #pragma unroll
    for (int k0 = 0; k0 < 32; k0 += 4) {
        const float4 x0 = *(const float4*)&sX[(k0+0)*Tv + t0];
        const float4 x1 = *(const float4*)&sX[(k0+1)*Tv + t0];
        const float4 x2 = *(const float4*)&sX[(k0+2)*Tv + t0];
        const float4 x3 = *(const float4*)&sX[(k0+3)*Tv + t0];
        { const float4 a = *(const float4*)&Mg[(cA+0)*DCv + k0]; GEMM_CC(oA,0,a) }
        { const float4 a = *(const float4*)&Mg[(cA+1)*DCv + k0]; GEMM_CC(oA,1,a) }
        { const float4 a = *(const float4*)&Mg[(cA+2)*DCv + k0]; GEMM_CC(oA,2,a) }
        { const float4 a = *(const float4*)&Mg[(cA+3)*DCv + k0]; GEMM_CC(oA,3,a) }
        { const float4 a = *(const float4*)&Mg[(cB+0)*DCv + k0]; GEMM_CC(oB,0,a) }
        { const float4 a = *(const float4*)&Mg[(cB+1)*DCv + k0]; GEMM_CC(oB,1,a) }
        { const float4 a = *(const float4*)&Mg[(cB+2)*DCv + k0]; GEMM_CC(oB,2,a) }
        { const float4 a = *(const float4*)&Mg[(cB+3)*DCv + k0]; GEMM_CC(oB,3,a) }
    }

    // ---- mask ----
    #pragma unroll
    for (int jt = 0; jt < 4; ++jt) {
        if (t0 + jt >= limit) {
            #pragma unroll
            for (int cc = 0; cc < 4; ++cc) { oA[cc*4+jt] = -INFINITY; oB[cc*4+jt] = -INFINITY; }
        }
    }

    // ---- ONLINE wave stats (one pass): m_w, s_w ----
    float mwA[4], mwB[4];
    #pragma unroll
    for (int cc = 0; cc < 4; ++cc) {
        float mA = fmaxf(fmaxf(oA[cc*4+0], oA[cc*4+1]), fmaxf(oA[cc*4+2], oA[cc*4+3]));
        float mB = fmaxf(fmaxf(oB[cc*4+0], oB[cc*4+1]), fmaxf(oB[cc*4+2], oB[cc*4+3]));
        #pragma unroll
        for (int s = 1; s < 16; s <<= 1) {
            mA = fmaxf(mA, __shfl_xor(mA, s));
            mB = fmaxf(mB, __shfl_xor(mB, s));
        }
        mA = fmaxf(mA, -1e30f);
        mB = fmaxf(mB, -1e30f);
        float sA = 0.f, sB = 0.f;
        #pragma unroll
        for (int jt = 0; jt < 4; ++jt) {
            oA[cc*4+jt] = __expf(oA[cc*4+jt] - mA); sA += oA[cc*4+jt];
            oB[cc*4+jt] = __expf(oB[cc*4+jt] - mB); sB += oB[cc*4+jt];
        }
        #pragma unroll
        for (int s = 1; s < 16; s <<= 1) {
            sA += __shfl_xor(sA, s);
            sB += __shfl_xor(sB, s);
        }
        mwA[cc] = mA; mwB[cc] = mB;
        if (tl == 0) {
            sPartM[w][cA + cc] = mA; sPartS[w][cA + cc] = sA;
            sPartM[w][cB + cc] = mB; sPartS[w][cB + cc] = sB;
        }
    }
    __syncthreads();
    if (tid < DCv) {
        float m = sPartM[0][tid];
        #pragma unroll
        for (int ww = 1; ww < 8; ++ww) m = fmaxf(m, sPartM[ww][tid]);
        float Z = 0.f;
        #pragma unroll
        for (int ww = 0; ww < 8; ++ww) Z += sPartS[ww][tid] * __expf(sPartM[ww][tid] - m);
        sMx[tid] = m;
        sRZ[tid] = 1.f / Z;
    }
    __syncthreads();

    // ---- P = e_w * exp(m_w - m) / Z -> overwrite sX ----
    #pragma unroll
    for (int cc = 0; cc < 4; ++cc) {
        const float scA = __expf(mwA[cc] - sMx[cA + cc]) * sRZ[cA + cc];
        const float scB = __expf(mwB[cc] - sMx[cB + cc]) * sRZ[cB + cc];
        float4 pA, pB;
        pA.x = oA[cc*4+0]*scA; pA.y = oA[cc*4+1]*scA; pA.z = oA[cc*4+2]*scA; pA.w = oA[cc*4+3]*scA;
        pB.x = oB[cc*4+0]*scB; pB.y = oB[cc*4+1]*scB; pB.z = oB[cc*4+2]*scB; pB.w = oB[cc*4+3]*scB;
        *(float4*)&sX[(cA + cc)*Tv + t0] = pA;
        *(float4*)&sX[(cB + cc)*Tv + t0] = pB;
    }
    __syncthreads();

    // ---- GEMM2: OUT[64oc][t]; A from GLOBAL raw wp (L1/L2-hot); scale after ----
    #pragma unroll 1
    for (int it = 0; it < 2; ++it) {
        const int oc0 = it * 32 + cl * 8;
        const float* Wg = wp + oc0 * DCv;

        float acc[32];
        #pragma unroll
        for (int i = 0; i < 32; ++i) acc[i] = 0.f;

        #pragma unroll
        for (int k0 = 0; k0 < 32; k0 += 4) {
            const float4 x0 = *(const float4*)&sX[(k0+0)*Tv + t0];
            const float4 x1 = *(const float4*)&sX[(k0+1)*Tv + t0];
            const float4 x2 = *(const float4*)&sX[(k0+2)*Tv + t0];
            const float4 x3 = *(const float4*)&sX[(k0+3)*Tv + t0];
            { const float4 a = *(const float4*)&Wg[0*DCv + k0]; GEMM_CC(acc,0,a) }
            { const float4 a = *(const float4*)&Wg[1*DCv + k0]; GEMM_CC(acc,1,a) }
            { const float4 a = *(const float4*)&Wg[2*DCv + k0]; GEMM_CC(acc,2,a) }
            { const float4 a = *(const float4*)&Wg[3*DCv + k0]; GEMM_CC(acc,3,a) }
            { const float4 a = *(const float4*)&Wg[4*DCv + k0]; GEMM_CC(acc,4,a) }
            { const float4 a = *(const float4*)&Wg[5*DCv + k0]; GEMM_CC(acc,5,a) }
            { const float4 a = *(const float4*)&Wg[6*DCv + k0]; GEMM_CC(acc,6,a) }
            { const float4 a = *(const float4*)&Wg[7*DCv + k0]; GEMM_CC(acc,7,a) }
        }

        const float* rp = inp + ((size_t)(b * Cv + oc0) * Fv + f) * Tv + t0;
        float*       po = out + ((size_t)(b * Cv + oc0) * Fv + f) * Tv + t0;
        #pragma unroll
        for (int r = 0; r < 8; ++r) {
            const float4 rv = *(const float4*)&rp[(size_t)r * FT];
            const float ss = sS2[oc0 + r];
            const float bb = sB2[oc0 + r];
            float z0 = fmaf(acc[r*4+0], ss, bb), z1 = fmaf(acc[r*4+1], ss, bb);
            float z2 = fmaf(acc[r*4+2], ss, bb), z3 = fmaf(acc[r*4+3], ss, bb);
            z0 = z0 >= 0.f ? z0 : alpha2 * z0;
            z1 = z1 >= 0.f ? z1 : alpha2 * z1;
            z2 = z2 >= 0.f ? z2 : alpha2 * z2;
            z3 = z3 >= 0.f ? z3 : alpha2 * z3;
            float4 o4; o4.x = z0 + rv.x; o4.y = z1 + rv.y;
            o4.z = z2 + rv.z; o4.w = z3 + rv.w;
            *(float4*)&po[(size_t)r * FT] = o4;
        }
    }
}

extern "C" void kernel_launch(void* const* d_in, const int* in_sizes, int n_in,
                              void* d_out, int out_size, void* d_ws, size_t ws_size,
                              hipStream_t stream) {
    const float* inp = (const float*)d_in[0];
    const float* w1  = (const float*)d_in[1];
    const float* b1  = (const float*)d_in[2];
    const float* g1  = (const float*)d_in[3];
    const float* be1 = (const float*)d_in[4];
    const float* m1  = (const float*)d_in[5];
    const float* v1  = (const float*)d_in[6];
    const float* a1  = (const float*)d_in[7];
    const float* wp  = (const float*)d_in[8];
    const float* bp  = (const float*)d_in[9];
    const float* g2  = (const float*)d_in[10];
    const float* be2 = (const float*)d_in[11];
    const float* m2  = (const float*)d_in[12];
    const float* v2  = (const float*)d_in[13];
    const float* a2  = (const float*)d_in[14];

    float* Qws   = (float*)d_ws;                            // 8,388,608 f = 33.6 MB
    float* Mfull = Qws + (size_t)Bv * Fv * Tv * DCv;        //   524,288 f =  2.1 MB

    kc1_conv<<<dim3(Bv * Fv * 2), dim3(256), 0, stream>>>(
        inp, w1, b1, g1, be1, m1, v1, a1, Qws);
    km_build<<<dim3(Bv * Fv), dim3(256), 0, stream>>>(Qws, Mfull);
    kf_fused<<<dim3(Bv * Fv), dim3(512), 0, stream>>>(
        inp, Qws, Mfull, wp, bp, g2, be2, m2, v2, a2, (float*)d_out);
}

// Round 22
// 87.185 us; speedup vs baseline: 1.6030x; 1.6030x over previous
//
#include <hip/hip_runtime.h>
#include <math.h>

#define Bv  4
#define Cv  64
#define DCv 32
#define Fv  128
#define Tv  512
#define FT  (Fv * 512)

// ---------------------------------------------------------------------------
// KC1: conv1, 8-row x 4-t register tile (~27 us). [r19/r20-proven]
// ---------------------------------------------------------------------------
__global__ __launch_bounds__(256, 4)
void kc1_conv(const float* __restrict__ inp,
              const float* __restrict__ w1, const float* __restrict__ b1,
              const float* __restrict__ g1, const float* __restrict__ be1,
              const float* __restrict__ m1, const float* __restrict__ v1,
              const float* __restrict__ a1,
              float* __restrict__ Qws)
{
    __shared__ __align__(16) float sW[Cv * DCv];   // 8 KB [k][c]
    __shared__ float sB[DCv];

    const int tid = threadIdx.x;
    const int bid = blockIdx.x;
    const int h   = bid & 1;
    const int bf  = bid >> 1;
    const int b   = bf >> 7;
    const int f   = bf & 127;

    #pragma unroll
    for (int i = 0; i < 8; ++i) {
        const int e = tid * 8 + i;
        const int c = e & 31, k = e >> 5;
        sW[e] = w1[c * Cv + k] * (g1[c] * rsqrtf(v1[c] + 1e-5f));
    }
    if (tid < DCv) {
        const float s = g1[tid] * rsqrtf(v1[tid] + 1e-5f);
        sB[tid] = (b1[tid] - m1[tid]) * s + be1[tid];
    }
    const float alpha1 = a1[0];
    __syncthreads();

    const int w  = tid >> 6, l = tid & 63;
    const int tl = l & 15, cl = l >> 4;
    const int r0 = cl * 8;
    const int t0 = h * 256 + w * 64 + tl * 4;

    const float* px = inp + (size_t)(b * Cv) * FT + f * 512 + t0;

    float acc[32];
    #pragma unroll
    for (int i = 0; i < 32; ++i) acc[i] = 0.f;

    #pragma unroll 8
    for (int k = 0; k < Cv; ++k) {
        const float4 x   = *(const float4*)&px[(size_t)k * FT];
        const float4 a0  = *(const float4*)&sW[k * DCv + r0];
        const float4 a1v = *(const float4*)&sW[k * DCv + r0 + 4];
        acc[0*4+0] = fmaf(a0.x, x.x, acc[0*4+0]); acc[0*4+1] = fmaf(a0.x, x.y, acc[0*4+1]);
        acc[0*4+2] = fmaf(a0.x, x.z, acc[0*4+2]); acc[0*4+3] = fmaf(a0.x, x.w, acc[0*4+3]);
        acc[1*4+0] = fmaf(a0.y, x.x, acc[1*4+0]); acc[1*4+1] = fmaf(a0.y, x.y, acc[1*4+1]);
        acc[1*4+2] = fmaf(a0.y, x.z, acc[1*4+2]); acc[1*4+3] = fmaf(a0.y, x.w, acc[1*4+3]);
        acc[2*4+0] = fmaf(a0.z, x.x, acc[2*4+0]); acc[2*4+1] = fmaf(a0.z, x.y, acc[2*4+1]);
        acc[2*4+2] = fmaf(a0.z, x.z, acc[2*4+2]); acc[2*4+3] = fmaf(a0.z, x.w, acc[2*4+3]);
        acc[3*4+0] = fmaf(a0.w, x.x, acc[3*4+0]); acc[3*4+1] = fmaf(a0.w, x.y, acc[3*4+1]);
        acc[3*4+2] = fmaf(a0.w, x.z, acc[3*4+2]); acc[3*4+3] = fmaf(a0.w, x.w, acc[3*4+3]);
        acc[4*4+0] = fmaf(a1v.x, x.x, acc[4*4+0]); acc[4*4+1] = fmaf(a1v.x, x.y, acc[4*4+1]);
        acc[4*4+2] = fmaf(a1v.x, x.z, acc[4*4+2]); acc[4*4+3] = fmaf(a1v.x, x.w, acc[4*4+3]);
        acc[5*4+0] = fmaf(a1v.y, x.x, acc[5*4+0]); acc[5*4+1] = fmaf(a1v.y, x.y, acc[5*4+1]);
        acc[5*4+2] = fmaf(a1v.y, x.z, acc[5*4+2]); acc[5*4+3] = fmaf(a1v.y, x.w, acc[5*4+3]);
        acc[6*4+0] = fmaf(a1v.z, x.x, acc[6*4+0]); acc[6*4+1] = fmaf(a1v.z, x.y, acc[6*4+1]);
        acc[6*4+2] = fmaf(a1v.z, x.z, acc[6*4+2]); acc[6*4+3] = fmaf(a1v.z, x.w, acc[6*4+3]);
        acc[7*4+0] = fmaf(a1v.w, x.x, acc[7*4+0]); acc[7*4+1] = fmaf(a1v.w, x.y, acc[7*4+1]);
        acc[7*4+2] = fmaf(a1v.w, x.z, acc[7*4+2]); acc[7*4+3] = fmaf(a1v.w, x.w, acc[7*4+3]);
    }

    const float b0 = sB[r0+0], b1_ = sB[r0+1], b2 = sB[r0+2], b3 = sB[r0+3];
    const float b4 = sB[r0+4], b5  = sB[r0+5], b6 = sB[r0+6], b7 = sB[r0+7];
    #pragma unroll
    for (int j = 0; j < 4; ++j) {
        float z0 = acc[0*4+j] + b0, z1 = acc[1*4+j] + b1_;
        float z2 = acc[2*4+j] + b2, z3 = acc[3*4+j] + b3;
        float z4 = acc[4*4+j] + b4, z5 = acc[5*4+j] + b5;
        float z6 = acc[6*4+j] + b6, z7 = acc[7*4+j] + b7;
        z0 = z0 >= 0.f ? z0 : alpha1 * z0;  z1 = z1 >= 0.f ? z1 : alpha1 * z1;
        z2 = z2 >= 0.f ? z2 : alpha1 * z2;  z3 = z3 >= 0.f ? z3 : alpha1 * z3;
        z4 = z4 >= 0.f ? z4 : alpha1 * z4;  z5 = z5 >= 0.f ? z5 : alpha1 * z5;
        z6 = z6 >= 0.f ? z6 : alpha1 * z6;  z7 = z7 >= 0.f ? z7 : alpha1 * z7;
        float4 v0; v0.x = z0; v0.y = z1; v0.z = z2; v0.w = z3;
        float4 v1; v1.x = z4; v1.y = z5; v1.z = z6; v1.w = z7;
        float* qg = Qws + ((size_t)bf * Tv + t0 + j) * DCv + r0;
        *(float4*)&qg[0] = v0;
        *(float4*)&qg[4] = v1;
    }
}

// ---------------------------------------------------------------------------
// KM: M = Q Q^T / sqrt(32). One block per bf (~9 us). [proven]
// ---------------------------------------------------------------------------
__global__ __launch_bounds__(256)
void km_build(const float* __restrict__ Qws, float* __restrict__ Mfull)
{
    __shared__ __align__(16) float sP[4][1024];  // 16 KB

    const int tid   = threadIdx.x;
    const int bf    = blockIdx.x;
    const int slice = tid >> 6;
    const int l     = tid & 63;
    const int c1b   = l >> 3;
    const int c2b   = l & 7;

    const float* qp = Qws + ((size_t)bf * Tv + slice * 128) * DCv;
    float4 r0 = {0,0,0,0}, r1 = {0,0,0,0}, r2 = {0,0,0,0}, r3 = {0,0,0,0};
    #pragma unroll 4
    for (int i = 0; i < 128; ++i) {
        const float4 qa = *(const float4*)&qp[i * 32 + c1b * 4];
        const float4 qb = *(const float4*)&qp[i * 32 + c2b * 4];
        r0.x = fmaf(qa.x, qb.x, r0.x); r0.y = fmaf(qa.x, qb.y, r0.y);
        r0.z = fmaf(qa.x, qb.z, r0.z); r0.w = fmaf(qa.x, qb.w, r0.w);
        r1.x = fmaf(qa.y, qb.x, r1.x); r1.y = fmaf(qa.y, qb.y, r1.y);
        r1.z = fmaf(qa.y, qb.z, r1.z); r1.w = fmaf(qa.y, qb.w, r1.w);
        r2.x = fmaf(qa.z, qb.x, r2.x); r2.y = fmaf(qa.z, qb.y, r2.y);
        r2.z = fmaf(qa.z, qb.z, r2.z); r2.w = fmaf(qa.z, qb.w, r2.w);
        r3.x = fmaf(qa.w, qb.x, r3.x); r3.y = fmaf(qa.w, qb.y, r3.y);
        r3.z = fmaf(qa.w, qb.z, r3.z); r3.w = fmaf(qa.w, qb.w, r3.w);
    }
    *(float4*)&sP[slice][(c1b * 4 + 0) * DCv + c2b * 4] = r0;
    *(float4*)&sP[slice][(c1b * 4 + 1) * DCv + c2b * 4] = r1;
    *(float4*)&sP[slice][(c1b * 4 + 2) * DCv + c2b * 4] = r2;
    *(float4*)&sP[slice][(c1b * 4 + 3) * DCv + c2b * 4] = r3;
    __syncthreads();

    const float INV = 0.17677669529663687f;  // 1/sqrt(32)
    float4 v0 = *(const float4*)&sP[0][tid * 4];
    float4 v1 = *(const float4*)&sP[1][tid * 4];
    float4 v2 = *(const float4*)&sP[2][tid * 4];
    float4 v3 = *(const float4*)&sP[3][tid * 4];
    float4 o;
    o.x = ((v0.x + v1.x) + (v2.x + v3.x)) * INV;
    o.y = ((v0.y + v1.y) + (v2.y + v3.y)) * INV;
    o.z = ((v0.z + v1.z) + (v2.z + v3.z)) * INV;
    o.w = ((v0.w + v1.w) + (v2.w + v3.w)) * INV;
    *(float4*)&Mfull[(size_t)bf * 1024 + tid * 4] = o;
}

// ---------------------------------------------------------------------------
// KF: fused O=M*Q -> mask -> online softmax -> P -> OUT=W2*P+B2 -> PReLU ->
// +residual. Champion r20 version (measured 48.5 us): LDS-staged sM/sW
// (broadcast A-path), sX [k][t] fp32, online softmax, 2-iteration GEMM2.
// ---------------------------------------------------------------------------
#define GEMM_CC(ACC, cc, a)                                       \
    ACC[(cc)*4+0] = fmaf(a.x, x0.x, ACC[(cc)*4+0]);               \
    ACC[(cc)*4+0] = fmaf(a.y, x1.x, ACC[(cc)*4+0]);               \
    ACC[(cc)*4+0] = fmaf(a.z, x2.x, ACC[(cc)*4+0]);               \
    ACC[(cc)*4+0] = fmaf(a.w, x3.x, ACC[(cc)*4+0]);               \
    ACC[(cc)*4+1] = fmaf(a.x, x0.y, ACC[(cc)*4+1]);               \
    ACC[(cc)*4+1] = fmaf(a.y, x1.y, ACC[(cc)*4+1]);               \
    ACC[(cc)*4+1] = fmaf(a.z, x2.y, ACC[(cc)*4+1]);               \
    ACC[(cc)*4+1] = fmaf(a.w, x3.y, ACC[(cc)*4+1]);               \
    ACC[(cc)*4+2] = fmaf(a.x, x0.z, ACC[(cc)*4+2]);               \
    ACC[(cc)*4+2] = fmaf(a.y, x1.z, ACC[(cc)*4+2]);               \
    ACC[(cc)*4+2] = fmaf(a.z, x2.z, ACC[(cc)*4+2]);               \
    ACC[(cc)*4+2] = fmaf(a.w, x3.z, ACC[(cc)*4+2]);               \
    ACC[(cc)*4+3] = fmaf(a.x, x0.w, ACC[(cc)*4+3]);               \
    ACC[(cc)*4+3] = fmaf(a.y, x1.w, ACC[(cc)*4+3]);               \
    ACC[(cc)*4+3] = fmaf(a.z, x2.w, ACC[(cc)*4+3]);               \
    ACC[(cc)*4+3] = fmaf(a.w, x3.w, ACC[(cc)*4+3]);

__global__ __launch_bounds__(512, 2)
void kf_fused(const float* __restrict__ inp,
              const float* __restrict__ Qws, const float* __restrict__ Mfull,
              const float* __restrict__ wp, const float* __restrict__ bp,
              const float* __restrict__ g2, const float* __restrict__ be2,
              const float* __restrict__ m2, const float* __restrict__ v2,
              const float* __restrict__ a2,
              float* __restrict__ out)
{
    __shared__ __align__(16) float sX[DCv * Tv];   // 64 KB [k][t]: Q, then P
    __shared__ __align__(16) float sM[DCv * 36];   // 4.5 KB
    __shared__ __align__(16) float sW[Cv * 36];    // 9 KB
    __shared__ float sPartM[8][DCv], sPartS[8][DCv];
    __shared__ float sMx[DCv], sRZ[DCv];
    __shared__ float sB2[Cv];

    const int tid = threadIdx.x;
    const int bf  = blockIdx.x;
    const int b   = bf >> 7;
    const int f   = bf & 127;
    const int w   = tid >> 6;
    const int l   = tid & 63;
    const int tl  = l & 15;
    const int cl  = l >> 4;
    const int t0  = w * 64 + tl * 4;          // this lane's 4 t-columns
    const int limit = f + (Tv - Fv + 1);      // valid iff t < limit (385..512)
    const float alpha2 = a2[0];

    // ---- stage: q column, M, W2 (BN-folded inline), B2 ----
    const float* qg = Qws + ((size_t)bf * Tv + tid) * DCv;
    float4 q0 = *(const float4*)&qg[0],  q1 = *(const float4*)&qg[4];
    float4 q2 = *(const float4*)&qg[8],  q3 = *(const float4*)&qg[12];
    float4 q4 = *(const float4*)&qg[16], q5 = *(const float4*)&qg[20];
    float4 q6 = *(const float4*)&qg[24], q7 = *(const float4*)&qg[28];

    if (tid < 256) {
        const int c = tid >> 3, k0 = (tid & 7) << 2;
        float4 v = *(const float4*)&Mfull[(size_t)bf * 1024 + tid * 4];
        *(float4*)&sM[c * 36 + k0] = v;
    }
    {
        const int c = tid >> 3, k0 = (tid & 7) << 2;
        const float s = g2[c] * rsqrtf(v2[c] + 1e-5f);
        float4 v = *(const float4*)&wp[tid * 4];
        v.x *= s; v.y *= s; v.z *= s; v.w *= s;
        *(float4*)&sW[c * 36 + k0] = v;
    }
    if (tid < Cv) {
        const float s = g2[tid] * rsqrtf(v2[tid] + 1e-5f);
        sB2[tid] = (bp[tid] - m2[tid]) * s + be2[tid];
    }

    {
        const int t = tid;
        sX[ 0*Tv+t]=q0.x; sX[ 1*Tv+t]=q0.y; sX[ 2*Tv+t]=q0.z; sX[ 3*Tv+t]=q0.w;
        sX[ 4*Tv+t]=q1.x; sX[ 5*Tv+t]=q1.y; sX[ 6*Tv+t]=q1.z; sX[ 7*Tv+t]=q1.w;
        sX[ 8*Tv+t]=q2.x; sX[ 9*Tv+t]=q2.y; sX[10*Tv+t]=q2.z; sX[11*Tv+t]=q2.w;
        sX[12*Tv+t]=q3.x; sX[13*Tv+t]=q3.y; sX[14*Tv+t]=q3.z; sX[15*Tv+t]=q3.w;
        sX[16*Tv+t]=q4.x; sX[17*Tv+t]=q4.y; sX[18*Tv+t]=q4.z; sX[19*Tv+t]=q4.w;
        sX[20*Tv+t]=q5.x; sX[21*Tv+t]=q5.y; sX[22*Tv+t]=q5.z; sX[23*Tv+t]=q5.w;
        sX[24*Tv+t]=q6.x; sX[25*Tv+t]=q6.y; sX[26*Tv+t]=q6.z; sX[27*Tv+t]=q6.w;
        sX[28*Tv+t]=q7.x; sX[29*Tv+t]=q7.y; sX[30*Tv+t]=q7.z; sX[31*Tv+t]=q7.w;
    }
    __syncthreads();

    // ---- GEMM1: O[32c][t], two 4-row tiles SHARING x-reads ----
    float oA[16], oB[16];
    #pragma unroll
    for (int i = 0; i < 16; ++i) { oA[i] = 0.f; oB[i] = 0.f; }
    const int cA = cl * 4;
    const int cB = 16 + cl * 4;
    #pragma unroll
    for (int k0 = 0; k0 < 32; k0 += 4) {
        const float4 x0 = *(const float4*)&sX[(k0+0)*Tv + t0];
        const float4 x1 = *(const float4*)&sX[(k0+1)*Tv + t0];
        const float4 x2 = *(const float4*)&sX[(k0+2)*Tv + t0];
        const float4 x3 = *(const float4*)&sX[(k0+3)*Tv + t0];
        { const float4 a = *(const float4*)&sM[(cA+0)*36 + k0]; GEMM_CC(oA,0,a) }
        { const float4 a = *(const float4*)&sM[(cA+1)*36 + k0]; GEMM_CC(oA,1,a) }
        { const float4 a = *(const float4*)&sM[(cA+2)*36 + k0]; GEMM_CC(oA,2,a) }
        { const float4 a = *(const float4*)&sM[(cA+3)*36 + k0]; GEMM_CC(oA,3,a) }
        { const float4 a = *(const float4*)&sM[(cB+0)*36 + k0]; GEMM_CC(oB,0,a) }
        { const float4 a = *(const float4*)&sM[(cB+1)*36 + k0]; GEMM_CC(oB,1,a) }
        { const float4 a = *(const float4*)&sM[(cB+2)*36 + k0]; GEMM_CC(oB,2,a) }
        { const float4 a = *(const float4*)&sM[(cB+3)*36 + k0]; GEMM_CC(oB,3,a) }
    }

    // ---- mask ----
    #pragma unroll
    for (int jt = 0; jt < 4; ++jt) {
        if (t0 + jt >= limit) {
            #pragma unroll
            for (int cc = 0; cc < 4; ++cc) { oA[cc*4+jt] = -INFINITY; oB[cc*4+jt] = -INFINITY; }
        }
    }

    // ---- ONLINE wave stats (one pass): m_w, s_w ----
    float mwA[4], mwB[4];
    #pragma unroll
    for (int cc = 0; cc < 4; ++cc) {
        float mA = fmaxf(fmaxf(oA[cc*4+0], oA[cc*4+1]), fmaxf(oA[cc*4+2], oA[cc*4+3]));
        float mB = fmaxf(fmaxf(oB[cc*4+0], oB[cc*4+1]), fmaxf(oB[cc*4+2], oB[cc*4+3]));
        #pragma unroll
        for (int s = 1; s < 16; s <<= 1) {
            mA = fmaxf(mA, __shfl_xor(mA, s));
            mB = fmaxf(mB, __shfl_xor(mB, s));
        }
        mA = fmaxf(mA, -1e30f);
        mB = fmaxf(mB, -1e30f);
        float sA = 0.f, sB = 0.f;
        #pragma unroll
        for (int jt = 0; jt < 4; ++jt) {
            oA[cc*4+jt] = __expf(oA[cc*4+jt] - mA); sA += oA[cc*4+jt];
            oB[cc*4+jt] = __expf(oB[cc*4+jt] - mB); sB += oB[cc*4+jt];
        }
        #pragma unroll
        for (int s = 1; s < 16; s <<= 1) {
            sA += __shfl_xor(sA, s);
            sB += __shfl_xor(sB, s);
        }
        mwA[cc] = mA; mwB[cc] = mB;
        if (tl == 0) {
            sPartM[w][cA + cc] = mA; sPartS[w][cA + cc] = sA;
            sPartM[w][cB + cc] = mB; sPartS[w][cB + cc] = sB;
        }
    }
    __syncthreads();
    if (tid < DCv) {
        float m = sPartM[0][tid];
        #pragma unroll
        for (int ww = 1; ww < 8; ++ww) m = fmaxf(m, sPartM[ww][tid]);
        float Z = 0.f;
        #pragma unroll
        for (int ww = 0; ww < 8; ++ww) Z += sPartS[ww][tid] * __expf(sPartM[ww][tid] - m);
        sMx[tid] = m;
        sRZ[tid] = 1.f / Z;
    }
    __syncthreads();

    // ---- P = e_w * exp(m_w - m) / Z -> overwrite sX ----
    #pragma unroll
    for (int cc = 0; cc < 4; ++cc) {
        const float scA = __expf(mwA[cc] - sMx[cA + cc]) * sRZ[cA + cc];
        const float scB = __expf(mwB[cc] - sMx[cB + cc]) * sRZ[cB + cc];
        float4 pA, pB;
        pA.x = oA[cc*4+0]*scA; pA.y = oA[cc*4+1]*scA; pA.z = oA[cc*4+2]*scA; pA.w = oA[cc*4+3]*scA;
        pB.x = oB[cc*4+0]*scB; pB.y = oB[cc*4+1]*scB; pB.z = oB[cc*4+2]*scB; pB.w = oB[cc*4+3]*scB;
        *(float4*)&sX[(cA + cc)*Tv + t0] = pA;
        *(float4*)&sX[(cB + cc)*Tv + t0] = pB;
    }
    __syncthreads();

    // ---- GEMM2: OUT[64oc][t] in TWO 8-row-tile iterations (x-reads shared) ----
    #pragma unroll 1
    for (int it = 0; it < 2; ++it) {
        const int oc0 = it * 32 + cl * 8;

        float acc[32];
        #pragma unroll
        for (int i = 0; i < 32; ++i) acc[i] = 0.f;

        #pragma unroll
        for (int k0 = 0; k0 < 32; k0 += 4) {
            const float4 x0 = *(const float4*)&sX[(k0+0)*Tv + t0];
            const float4 x1 = *(const float4*)&sX[(k0+1)*Tv + t0];
            const float4 x2 = *(const float4*)&sX[(k0+2)*Tv + t0];
            const float4 x3 = *(const float4*)&sX[(k0+3)*Tv + t0];
            { const float4 a = *(const float4*)&sW[(oc0+0)*36 + k0]; GEMM_CC(acc,0,a) }
            { const float4 a = *(const float4*)&sW[(oc0+1)*36 + k0]; GEMM_CC(acc,1,a) }
            { const float4 a = *(const float4*)&sW[(oc0+2)*36 + k0]; GEMM_CC(acc,2,a) }
            { const float4 a = *(const float4*)&sW[(oc0+3)*36 + k0]; GEMM_CC(acc,3,a) }
            { const float4 a = *(const float4*)&sW[(oc0+4)*36 + k0]; GEMM_CC(acc,4,a) }
            { const float4 a = *(const float4*)&sW[(oc0+5)*36 + k0]; GEMM_CC(acc,5,a) }
            { const float4 a = *(const float4*)&sW[(oc0+6)*36 + k0]; GEMM_CC(acc,6,a) }
            { const float4 a = *(const float4*)&sW[(oc0+7)*36 + k0]; GEMM_CC(acc,7,a) }
        }

        const float* rp = inp + ((size_t)(b * Cv + oc0) * Fv + f) * Tv + t0;
        float*       po = out + ((size_t)(b * Cv + oc0) * Fv + f) * Tv + t0;
        #pragma unroll
        for (int r = 0; r < 8; ++r) {
            const float4 rv = *(const float4*)&rp[(size_t)r * FT];
            const float bb = sB2[oc0 + r];
            float z0 = acc[r*4+0] + bb, z1 = acc[r*4+1] + bb;
            float z2 = acc[r*4+2] + bb, z3 = acc[r*4+3] + bb;
            z0 = z0 >= 0.f ? z0 : alpha2 * z0;
            z1 = z1 >= 0.f ? z1 : alpha2 * z1;
            z2 = z2 >= 0.f ? z2 : alpha2 * z2;
            z3 = z3 >= 0.f ? z3 : alpha2 * z3;
            float4 o4; o4.x = z0 + rv.x; o4.y = z1 + rv.y;
            o4.z = z2 + rv.z; o4.w = z3 + rv.w;
            *(float4*)&po[(size_t)r * FT] = o4;
        }
    }
}

extern "C" void kernel_launch(void* const* d_in, const int* in_sizes, int n_in,
                              void* d_out, int out_size, void* d_ws, size_t ws_size,
                              hipStream_t stream) {
    const float* inp = (const float*)d_in[0];
    const float* w1  = (const float*)d_in[1];
    const float* b1  = (const float*)d_in[2];
    const float* g1  = (const float*)d_in[3];
    const float* be1 = (const float*)d_in[4];
    const float* m1  = (const float*)d_in[5];
    const float* v1  = (const float*)d_in[6];
    const float* a1  = (const float*)d_in[7];
    const float* wp  = (const float*)d_in[8];
    const float* bp  = (const float*)d_in[9];
    const float* g2  = (const float*)d_in[10];
    const float* be2 = (const float*)d_in[11];
    const float* m2  = (const float*)d_in[12];
    const float* v2  = (const float*)d_in[13];
    const float* a2  = (const float*)d_in[14];

    float* Qws   = (float*)d_ws;                            // 8,388,608 f = 33.6 MB
    float* Mfull = Qws + (size_t)Bv * Fv * Tv * DCv;        //   524,288 f =  2.1 MB

    kc1_conv<<<dim3(Bv * Fv * 2), dim3(256), 0, stream>>>(
        inp, w1, b1, g1, be1, m1, v1, a1, Qws);
    km_build<<<dim3(Bv * Fv), dim3(256), 0, stream>>>(Qws, Mfull);
    kf_fused<<<dim3(Bv * Fv), dim3(512), 0, stream>>>(
        inp, Qws, Mfull, wp, bp, g2, be2, m2, v2, a2, (float*)d_out);
}